// Round 2
// baseline (519.688 us; speedup 1.0000x reference)
//
#include <hip/hip_runtime.h>

#define H    64
#define TT   512
#define NB   16
#define OUTD 3
#define BTOT 4096
#define INF  6

typedef _Float16 f16;
typedef _Float16 f16x8 __attribute__((ext_vector_type(8)));
typedef float    f32x4 __attribute__((ext_vector_type(4)));
typedef float    f32x2 __attribute__((ext_vector_type(2)));

// plane row stride (f16 elems): cols 0-63 h0 | 64-127 h1 | 128-135 x | pad
#define AS 168

#define LOG2E 1.44269504088896340736f
#define KSC   (2.0f * LOG2E)

static __device__ __forceinline__ f32x2 pk_fma(f32x2 a, f32x2 b, f32x2 c) {
#if __has_builtin(__builtin_elementwise_fma)
    return __builtin_elementwise_fma(a, b, c);
#else
    f32x2 r; r.x = __builtin_fmaf(a.x, b.x, c.x); r.y = __builtin_fmaf(a.y, b.y, c.y);
    return r;
#endif
}

static __device__ __forceinline__ f32x2 pk_min(f32x2 a, f32x2 b) {
#if __has_builtin(__builtin_elementwise_min)
    return __builtin_elementwise_min(a, b);
#else
    f32x2 r; r.x = fminf(a.x, b.x); r.y = fminf(a.y, b.y);
    return r;
#endif
}

// Fused LSTM cell update for a ROW PAIR, on float2 ext-vectors so the backend
// emits v_pk_{add,mul,fma}_f32. Pre-activations arrive pre-scaled: ai,af,ao by
// log2e; ag by 2*log2e. C is the cell state pre-scaled by 2*log2e, updated in
// place. Returns h pair. Transcendentals (exp2/rcp, quarter-rate, no packed
// form) stay scalar: 14 per pair — the hard VALU floor of the cell.
__device__ __forceinline__ f32x2 lstm_cell2(f32x2 ai, f32x2 af, f32x2 ag, f32x2 ao,
                                            f32x2& C) {
    f32x2 ei, ef, eg, eo;
    ei.x = __builtin_amdgcn_exp2f(ai.x); ei.y = __builtin_amdgcn_exp2f(ai.y);
    ef.x = __builtin_amdgcn_exp2f(af.x); ef.y = __builtin_amdgcn_exp2f(af.y);
    eg.x = __builtin_amdgcn_exp2f(ag.x); eg.y = __builtin_amdgcn_exp2f(ag.y);
    eo.x = __builtin_amdgcn_exp2f(ao.x); eo.y = __builtin_amdgcn_exp2f(ao.y);
    f32x2 A  = ei + 1.0f;          // sigmoid(i) = ei/A
    f32x2 F  = ef + 1.0f;          // sigmoid(f) = ef/F
    f32x2 Bp = eg + 1.0f;          // tanh(g)    = (eg-1)/Bp
    f32x2 G  = eg - 1.0f;
    f32x2 P  = A * Bp;
    f32x2 PF = P * F;
    f32x2 r1; r1.x = __builtin_amdgcn_rcpf(PF.x); r1.y = __builtin_amdgcn_rcpf(PF.y);
    f32x2 n1 = ef * C * P;         // sigmoid(f)*C  * (P*F)
    f32x2 t2 = ei * G * F;         // i*g           * (P*F) / K
    f32x2 k2 = {KSC, KSC};
    C = pk_fma(k2, t2, n1) * r1;
    // h = sigmoid(o) * tanh(c):  ec = 2^C (C already 2*log2e*c), clamped vs inf
    f32x2 clim = {126.0f, 126.0f};
    f32x2 Cc = pk_min(C, clim);
    f32x2 ec; ec.x = __builtin_amdgcn_exp2f(Cc.x); ec.y = __builtin_amdgcn_exp2f(Cc.y);
    f32x2 D2 = (eo + 1.0f) * (ec + 1.0f);
    f32x2 r2; r2.x = __builtin_amdgcn_rcpf(D2.x); r2.y = __builtin_amdgcn_rcpf(D2.y);
    return eo * (ec - 1.0f) * r2;
}

// Wave-specialized layer pipeline, 16 waves (1024 threads):
//   pair = (t>>8)&3:  role = pair&1  (0: layer-0, 1: layer-1)
//                     rr   = pair>>1 (0: acc rows 0-1, 1: acc rows 2-3)
// The rr=0/rr=1 waves of a role redundantly compute the SAME MFMAs (matrix
// pipe was at 27% — duplication is free) and split the CELL math by
// accumulator register row, keeping all 64 lanes dense in the trans-heavy
// phase. Total trans issue per SIMD unchanged; waves/SIMD 2 -> 4 so the
// post-barrier LDS latency + trans-unit serialization overlap across waves.
// One barrier per slot. h0(s) -> plane s&1 cols 0-63; h1(s-1) -> plane (s-1)&1
// cols 64-127; x(s) -> plane s&1 cols 128+. Same-slot ranges disjoint.
__launch_bounds__(1024, 4)
__global__ void lstm_ws(const float* __restrict__ x,
                        const float* __restrict__ Wih0, const float* __restrict__ Whh0,
                        const float* __restrict__ bih0, const float* __restrict__ bhh0,
                        const float* __restrict__ Wih1, const float* __restrict__ Whh1,
                        const float* __restrict__ bih1, const float* __restrict__ bhh1,
                        const float* __restrict__ Wfc,  const float* __restrict__ bfc,
                        float* __restrict__ out)
{
    __shared__ __align__(16) f16 Phi[2][NB * AS];
    __shared__ float hfin[NB][H + 1];

    const int t    = threadIdx.x;
    const int u    = t & 255;
    const int pair = (t >> 8) & 3;
    const int role = pair & 1;
    const int rr   = pair >> 1;       // which acc-row pair this wave owns
    const int wv   = u >> 6;
    const int l15  = u & 15;
    const int q    = (u >> 4) & 3;
    const int jj   = 16 * wv + l15;   // hidden column this thread owns (all 4 gates)
    const int b0   = blockIdx.x * NB;
    const int ar   = l15 * AS;
    const int ko   = q * 8;

    // ---- zero both planes ----
    {
        f16* ph = &Phi[0][0];
        for (int idx = t; idx < 2 * NB * AS; idx += 1024) ph[idx] = (f16)0.0f;
    }
    __syncthreads();   // zeroing complete before x(0) store

    const bool loader = (pair == 0) && (u < NB * INF);
    const int  xb = u / INF;
    const int  xf = u - xb * INF;
    if (loader)
        Phi[0][xb * AS + 128 + xf] = (f16)x[((size_t)(b0 + xb) * TT) * INF + xf];
    __syncthreads();

    if (role == 0) {
        // ================= LAYER-0 waves =================
        f16x8 wh0[2][4];   // Whh0 fragments, pre-scaled
        f16x8 wx0[4];      // Wih0 x-tile (k<6 valid on q==0)
        f32x4 bC0[4];      // bias splat, persistent C operand for first MFMA
        #pragma unroll
        for (int g = 0; g < 4; ++g) {
            const float sc = (g == 2) ? (2.0f * LOG2E) : LOG2E;
            const int n = 64 * g + jj;
            #pragma unroll
            for (int kt = 0; kt < 2; ++kt) {
                f16x8 v;
                #pragma unroll
                for (int j = 0; j < 8; ++j)
                    v[j] = (f16)(Whh0[n * H + kt * 32 + q * 8 + j] * sc);
                wh0[kt][g] = v;
            }
            f16x8 vx;
            #pragma unroll
            for (int j = 0; j < 8; ++j)
                vx[j] = (q == 0 && j < INF) ? (f16)(Wih0[n * INF + j] * sc) : (f16)0.0f;
            wx0[g] = vx;
            const float bu = (bih0[64 * g + jj] + bhh0[64 * g + jj]) * sc;
            bC0[g] = (f32x4){bu, bu, bu, bu};
        }
        f32x2 c2 = {0.f, 0.f};   // this wave's 2 rows of cell state (pre-scaled)
        float xpre = 0.0f;

        // AH = plane p^1 (h0(s-1) read, x(s+1) write); BH = plane p (x(s) read, h0(s) write)
        auto stepL0 = [&](f16* __restrict__ AH, f16* __restrict__ BH, int s) {
            if (loader) {
                const int tn = (s + 1 < TT) ? (s + 1) : (TT - 1);
                xpre = x[((size_t)(b0 + xb) * TT + tn) * INF + xf];
            }
            f16x8 a0 = *(const f16x8*)&AH[ar + 0   + ko];
            f16x8 a1 = *(const f16x8*)&AH[ar + 32  + ko];
            f16x8 ax = *(const f16x8*)&BH[ar + 128 + ko];
            f32x4 accA[4];
            #pragma unroll
            for (int g = 0; g < 4; ++g) {
                f32x4 acc;   // bias enters as the C operand: no per-step init movs
                acc = __builtin_amdgcn_mfma_f32_16x16x32_f16(a0, wh0[0][g], bC0[g], 0, 0, 0);
                acc = __builtin_amdgcn_mfma_f32_16x16x32_f16(a1, wh0[1][g], acc, 0, 0, 0);
                acc = __builtin_amdgcn_mfma_f32_16x16x32_f16(ax, wx0[g],    acc, 0, 0, 0);
                accA[g] = acc;
            }
            if (rr == 0) {   // wave-uniform branch, static acc indices
                f32x2 hv = lstm_cell2((f32x2){accA[0][0], accA[0][1]},
                                      (f32x2){accA[1][0], accA[1][1]},
                                      (f32x2){accA[2][0], accA[2][1]},
                                      (f32x2){accA[3][0], accA[3][1]}, c2);
                BH[(q * 4 + 0) * AS + jj] = (f16)hv.x;
                BH[(q * 4 + 1) * AS + jj] = (f16)hv.y;
            } else {
                f32x2 hv = lstm_cell2((f32x2){accA[0][2], accA[0][3]},
                                      (f32x2){accA[1][2], accA[1][3]},
                                      (f32x2){accA[2][2], accA[2][3]},
                                      (f32x2){accA[3][2], accA[3][3]}, c2);
                BH[(q * 4 + 2) * AS + jj] = (f16)hv.x;
                BH[(q * 4 + 3) * AS + jj] = (f16)hv.y;
            }
            if (loader) AH[xb * AS + 128 + xf] = (f16)xpre;
            __syncthreads();
        };

        for (int s = 0; s < TT; s += 2) {
            stepL0(Phi[1], Phi[0], s);
            stepL0(Phi[0], Phi[1], s + 1);
        }
        __syncthreads();   // slot TT (layer-1 finishes h1(TT-1))
    } else {
        // ================= LAYER-1 waves =================
        f16x8 wi1[2][4];   // Wih1 (input = h0)
        f16x8 wh1[2][4];   // Whh1 (recurrent h1)
        f32x4 bC1[4];      // bias splat, persistent C operand for first MFMA
        #pragma unroll
        for (int g = 0; g < 4; ++g) {
            const float sc = (g == 2) ? (2.0f * LOG2E) : LOG2E;
            const int n = 64 * g + jj;
            #pragma unroll
            for (int kt = 0; kt < 2; ++kt) {
                f16x8 v1, v2;
                #pragma unroll
                for (int j = 0; j < 8; ++j) {
                    const int k = kt * 32 + q * 8 + j;
                    v1[j] = (f16)(Wih1[n * H + k] * sc);
                    v2[j] = (f16)(Whh1[n * H + k] * sc);
                }
                wi1[kt][g] = v1; wh1[kt][g] = v2;
            }
            const float bu = (bih1[64 * g + jj] + bhh1[64 * g + jj]) * sc;
            bC1[g] = (f32x4){bu, bu, bu, bu};
        }
        f32x2 c2 = {0.f, 0.f};   // this wave's 2 rows of cell state (pre-scaled)

        __syncthreads();   // slot 0 (layer-0 produces h0(0))

        // AH = plane p^1 (h0(s-1) read, h1(s-1) write); BH = plane p (h1(s-2) read)
        auto stepL1 = [&](f16* __restrict__ AH, f16* __restrict__ BH, int s) {
            f16x8 n0 = *(const f16x8*)&AH[ar + 0  + ko];
            f16x8 n1 = *(const f16x8*)&AH[ar + 32 + ko];
            f16x8 r0 = *(const f16x8*)&BH[ar + 64 + ko];
            f16x8 r1 = *(const f16x8*)&BH[ar + 96 + ko];
            f32x4 accB[4];
            #pragma unroll
            for (int g = 0; g < 4; ++g) {
                f32x4 acc;   // bias enters as the C operand: no per-step init movs
                acc = __builtin_amdgcn_mfma_f32_16x16x32_f16(n0, wi1[0][g], bC1[g], 0, 0, 0);
                acc = __builtin_amdgcn_mfma_f32_16x16x32_f16(n1, wi1[1][g], acc, 0, 0, 0);
                acc = __builtin_amdgcn_mfma_f32_16x16x32_f16(r0, wh1[0][g], acc, 0, 0, 0);
                acc = __builtin_amdgcn_mfma_f32_16x16x32_f16(r1, wh1[1][g], acc, 0, 0, 0);
                accB[g] = acc;
            }
            if (rr == 0) {   // wave-uniform branch, static acc indices
                f32x2 hv = lstm_cell2((f32x2){accB[0][0], accB[0][1]},
                                      (f32x2){accB[1][0], accB[1][1]},
                                      (f32x2){accB[2][0], accB[2][1]},
                                      (f32x2){accB[3][0], accB[3][1]}, c2);
                AH[(q * 4 + 0) * AS + 64 + jj] = (f16)hv.x;
                AH[(q * 4 + 1) * AS + 64 + jj] = (f16)hv.y;
                if (s == TT) {
                    hfin[q * 4 + 0][jj] = hv.x;
                    hfin[q * 4 + 1][jj] = hv.y;
                }
            } else {
                f32x2 hv = lstm_cell2((f32x2){accB[0][2], accB[0][3]},
                                      (f32x2){accB[1][2], accB[1][3]},
                                      (f32x2){accB[2][2], accB[2][3]},
                                      (f32x2){accB[3][2], accB[3][3]}, c2);
                AH[(q * 4 + 2) * AS + 64 + jj] = (f16)hv.x;
                AH[(q * 4 + 3) * AS + 64 + jj] = (f16)hv.y;
                if (s == TT) {
                    hfin[q * 4 + 2][jj] = hv.x;
                    hfin[q * 4 + 3][jj] = hv.y;
                }
            }
            __syncthreads();
        };

        for (int s = 1; s <= TT; s += 2) {
            stepL1(Phi[0], Phi[1], s);
            stepL1(Phi[1], Phi[0], s + 1);
        }
    }

    // ---- FC epilogue ----
    if (t < NB * OUTD) {
        const int b = t / OUTD;
        const int o = t - b * OUTD;
        float a = bfc[o];
        #pragma unroll
        for (int j = 0; j < H; ++j)
            a += Wfc[o * H + j] * hfin[b][j];
        out[(size_t)(b0 + b) * OUTD + o] = a;
    }
}

extern "C" void kernel_launch(void* const* d_in, const int* in_sizes, int n_in,
                              void* d_out, int out_size, void* d_ws, size_t ws_size,
                              hipStream_t stream) {
    const float* x    = (const float*)d_in[0];
    const float* Wih0 = (const float*)d_in[1];
    const float* Whh0 = (const float*)d_in[2];
    const float* bih0 = (const float*)d_in[3];
    const float* bhh0 = (const float*)d_in[4];
    const float* Wih1 = (const float*)d_in[5];
    const float* Whh1 = (const float*)d_in[6];
    const float* bih1 = (const float*)d_in[7];
    const float* bhh1 = (const float*)d_in[8];
    const float* Wfc  = (const float*)d_in[9];
    const float* bfc  = (const float*)d_in[10];

    dim3 grid(BTOT / NB);   // 256 blocks, 1 per CU; 16 waves = 4 waves/SIMD
    dim3 block(1024);
    lstm_ws<<<grid, block, 0, stream>>>(x, Wih0, Whh0, bih0, bhh0,
                                        Wih1, Whh1, bih1, bhh1,
                                        Wfc, bfc, (float*)d_out);
}

// Round 3
// 494.789 us; speedup vs baseline: 1.0503x; 1.0503x over previous
//
#include <hip/hip_runtime.h>

#define H    64
#define TT   512
#define NB   16
#define OUTD 3
#define BTOT 4096
#define INF  6
#define RD   4          // ring depth (h0 may lead h1 by up to 4 steps)
#define HS   72         // h ring row stride in f16 (144 B = 9*16 B, keeps b128 aligned)
#define XS   32         // x ring row stride in f16 (64 B); cols 6..31 stay zero

typedef _Float16 f16;
typedef _Float16 f16x8 __attribute__((ext_vector_type(8)));
typedef float    f32x4 __attribute__((ext_vector_type(4)));
typedef float    f32x2 __attribute__((ext_vector_type(2)));

#define LOG2E 1.44269504088896340736f
#define KSC   (2.0f * LOG2E)

static __device__ __forceinline__ f32x2 pk_fma(f32x2 a, f32x2 b, f32x2 c) {
#if __has_builtin(__builtin_elementwise_fma)
    return __builtin_elementwise_fma(a, b, c);
#else
    f32x2 r; r.x = __builtin_fmaf(a.x, b.x, c.x); r.y = __builtin_fmaf(a.y, b.y, c.y);
    return r;
#endif
}

static __device__ __forceinline__ f32x2 pk_min(f32x2 a, f32x2 b) {
#if __has_builtin(__builtin_elementwise_min)
    return __builtin_elementwise_min(a, b);
#else
    f32x2 r; r.x = fminf(a.x, b.x); r.y = fminf(a.y, b.y);
    return r;
#endif
}

// Fused LSTM cell update for a ROW PAIR (packed f32 ops). Pre-activations
// pre-scaled: ai,af,ao by log2e; ag by 2*log2e. C pre-scaled by 2*log2e,
// updated in place. 14 scalar transcendentals per pair = the VALU floor.
__device__ __forceinline__ f32x2 lstm_cell2(f32x2 ai, f32x2 af, f32x2 ag, f32x2 ao,
                                            f32x2& C) {
    f32x2 ei, ef, eg, eo;
    ei.x = __builtin_amdgcn_exp2f(ai.x); ei.y = __builtin_amdgcn_exp2f(ai.y);
    ef.x = __builtin_amdgcn_exp2f(af.x); ef.y = __builtin_amdgcn_exp2f(af.y);
    eg.x = __builtin_amdgcn_exp2f(ag.x); eg.y = __builtin_amdgcn_exp2f(ag.y);
    eo.x = __builtin_amdgcn_exp2f(ao.x); eo.y = __builtin_amdgcn_exp2f(ao.y);
    f32x2 A  = ei + 1.0f;
    f32x2 F  = ef + 1.0f;
    f32x2 Bp = eg + 1.0f;
    f32x2 G  = eg - 1.0f;
    f32x2 P  = A * Bp;
    f32x2 PF = P * F;
    f32x2 r1; r1.x = __builtin_amdgcn_rcpf(PF.x); r1.y = __builtin_amdgcn_rcpf(PF.y);
    f32x2 n1 = ef * C * P;
    f32x2 t2 = ei * G * F;
    f32x2 k2 = {KSC, KSC};
    C = pk_fma(k2, t2, n1) * r1;
    f32x2 clim = {126.0f, 126.0f};
    f32x2 Cc = pk_min(C, clim);
    f32x2 ec; ec.x = __builtin_amdgcn_exp2f(Cc.x); ec.y = __builtin_amdgcn_exp2f(Cc.y);
    f32x2 D2 = (eo + 1.0f) * (ec + 1.0f);
    f32x2 r2; r2.x = __builtin_amdgcn_rcpf(D2.x); r2.y = __builtin_amdgcn_rcpf(D2.y);
    return eo * (ec - 1.0f) * r2;
}

// Spin until a monotonic LDS counter reaches tgt. Volatile read -> ds_read_b32
// per poll (broadcast, conflict-free). Trailing compiler barrier prevents
// hoisting subsequent ds_reads above the wait.
static __device__ __forceinline__ void wait_ge(const unsigned* p, unsigned tgt) {
    volatile const unsigned* vp = (volatile const unsigned*)p;
    while (*vp < tgt) {}
    asm volatile("" ::: "memory");
}

// Retire all outstanding LDS ops, then one lane bumps the counter.
static __device__ __forceinline__ void bump(unsigned* p, bool lane0) {
    asm volatile("s_waitcnt lgkmcnt(0)" ::: "memory");
    if (lane0) atomicAdd(p, 1u);
}

// Decoupled wave-specialized pipeline, 8 waves (512 threads), NO per-step
// barrier. Waves 0-3: layer-0 step s; waves 4-7: layer-1 step m (runs 0..4
// steps behind). LDS rings (depth 4): H0r (h0), H1r (h1), Xr (x). Flags:
//   flg[0..3]  f0[j]: L0 waves bump after writing h0(s), s&3==j (also orders x(s+1))
//   flg[4..7]  f1[j]: L1 waves bump after writing h1(m)
//   flg[8..11] d0[j]: L1 waves bump after consuming h0(m) -> L0 may reuse slot
// Ready target for h(s): 4*(s>>2)+4. Overwrite target for h0(s), s>=4:
// d0[s&3] >= 4*(s>>2). Intra-group reuse is implied by group progress.
// Slot (s-1)&3 == 3 for s==0 reads the zero-initialized slot (h(-1)=0).
__launch_bounds__(512, 2)
__global__ void lstm_ws(const float* __restrict__ x,
                        const float* __restrict__ Wih0, const float* __restrict__ Whh0,
                        const float* __restrict__ bih0, const float* __restrict__ bhh0,
                        const float* __restrict__ Wih1, const float* __restrict__ Whh1,
                        const float* __restrict__ bih1, const float* __restrict__ bhh1,
                        const float* __restrict__ Wfc,  const float* __restrict__ bfc,
                        float* __restrict__ out)
{
    __shared__ __align__(16) f16 H0r[RD][NB * HS];
    __shared__ __align__(16) f16 H1r[RD][NB * HS];
    __shared__ __align__(16) f16 Xr[RD][NB * XS];
    __shared__ float hfin[NB][H + 1];
    __shared__ unsigned flg[12];

    const int t     = threadIdx.x;
    const int u     = t & 255;
    const int role  = t >> 8;
    const int wv    = u >> 6;
    const int l15   = u & 15;
    const int q     = (u >> 4) & 3;
    const int jj    = 16 * wv + l15;   // hidden column this thread owns (all 4 gates)
    const int b0    = blockIdx.x * NB;
    const int ar    = l15 * HS;
    const int ko    = q * 8;
    const bool lane0 = (t & 63) == 0;

    // ---- zero rings + flags ----
    for (int idx = t; idx < RD * NB * HS; idx += 512) (&H0r[0][0])[idx] = (f16)0.0f;
    for (int idx = t; idx < RD * NB * HS; idx += 512) (&H1r[0][0])[idx] = (f16)0.0f;
    for (int idx = t; idx < RD * NB * XS; idx += 512) (&Xr[0][0])[idx]  = (f16)0.0f;
    if (t < 12) flg[t] = 0u;
    __syncthreads();

    const bool loader = (role == 0) && (u < NB * INF);
    const int  xb = u / INF;
    const int  xf = u - xb * INF;
    if (loader)
        Xr[0][xb * XS + xf] = (f16)x[((size_t)(b0 + xb) * TT) * INF + xf];
    __syncthreads();

    if (role == 0) {
        // ================= LAYER-0 waves =================
        f16x8 wh0[2][4];   // Whh0 fragments, pre-scaled
        f16x8 wx0[4];      // Wih0 x-tile (k<6 valid on q==0)
        f32x4 bC0[4];      // bias splat, C operand of first MFMA
        #pragma unroll
        for (int g = 0; g < 4; ++g) {
            const float sc = (g == 2) ? (2.0f * LOG2E) : LOG2E;
            const int n = 64 * g + jj;
            #pragma unroll
            for (int kt = 0; kt < 2; ++kt) {
                f16x8 v;
                #pragma unroll
                for (int j = 0; j < 8; ++j)
                    v[j] = (f16)(Whh0[n * H + kt * 32 + q * 8 + j] * sc);
                wh0[kt][g] = v;
            }
            f16x8 vx;
            #pragma unroll
            for (int j = 0; j < 8; ++j)
                vx[j] = (q == 0 && j < INF) ? (f16)(Wih0[n * INF + j] * sc) : (f16)0.0f;
            wx0[g] = vx;
            const float bu = (bih0[64 * g + jj] + bhh0[64 * g + jj]) * sc;
            bC0[g] = (f32x4){bu, bu, bu, bu};
        }
        f32x2 c01 = {0.f, 0.f}, c23 = {0.f, 0.f};
        float xpre = 0.0f;

        #pragma unroll 4
        for (int s = 0; s < TT; ++s) {
            const int j  = s & 3;
            const int jp = (s - 1) & 3;   // == 3 at s==0 (zero slot)
            const int jn = (s + 1) & 3;
            // h0(s-1) ready (all 4 L0 waves) — also orders x(s) visibility
            if (s > 0) wait_ge(&flg[jp], 4u * (unsigned)((s - 1) >> 2) + 4u);
            if (loader) {
                const int tn = (s + 1 < TT) ? (s + 1) : (TT - 1);
                xpre = x[((size_t)(b0 + xb) * TT + tn) * INF + xf];
            }
            const f16* Ah = &H0r[jp][0];
            f16x8 a0 = *(const f16x8*)&Ah[ar + 0  + ko];
            f16x8 a1 = *(const f16x8*)&Ah[ar + 32 + ko];
            f16x8 ax = *(const f16x8*)&Xr[j][l15 * XS + ko];
            f32x4 accA[4];
            #pragma unroll
            for (int g = 0; g < 4; ++g) {
                f32x4 acc;
                acc = __builtin_amdgcn_mfma_f32_16x16x32_f16(a0, wh0[0][g], bC0[g], 0, 0, 0);
                acc = __builtin_amdgcn_mfma_f32_16x16x32_f16(a1, wh0[1][g], acc, 0, 0, 0);
                acc = __builtin_amdgcn_mfma_f32_16x16x32_f16(ax, wx0[g],    acc, 0, 0, 0);
                accA[g] = acc;
            }
            f32x2 h01 = lstm_cell2((f32x2){accA[0][0], accA[0][1]},
                                   (f32x2){accA[1][0], accA[1][1]},
                                   (f32x2){accA[2][0], accA[2][1]},
                                   (f32x2){accA[3][0], accA[3][1]}, c01);
            f32x2 h23 = lstm_cell2((f32x2){accA[0][2], accA[0][3]},
                                   (f32x2){accA[1][2], accA[1][3]},
                                   (f32x2){accA[2][2], accA[2][3]},
                                   (f32x2){accA[3][2], accA[3][3]}, c23);
            // slot-reuse safety: L1 must have consumed h0(s-4) (wait as late
            // as possible so MFMA+cell overlap any residual lag)
            if (s >= RD) wait_ge(&flg[8 + j], 4u * (unsigned)(s >> 2));
            f16* Bh = &H0r[j][0];
            Bh[(q * 4 + 0) * HS + jj] = (f16)h01.x;
            Bh[(q * 4 + 1) * HS + jj] = (f16)h01.y;
            Bh[(q * 4 + 2) * HS + jj] = (f16)h23.x;
            Bh[(q * 4 + 3) * HS + jj] = (f16)h23.y;
            if (loader) Xr[jn][xb * XS + xf] = (f16)xpre;
            bump(&flg[j], lane0);
        }
    } else {
        // ================= LAYER-1 waves =================
        f16x8 wi1[2][4];   // Wih1 (input = h0)
        f16x8 wh1[2][4];   // Whh1 (recurrent h1)
        f32x4 bC1[4];
        #pragma unroll
        for (int g = 0; g < 4; ++g) {
            const float sc = (g == 2) ? (2.0f * LOG2E) : LOG2E;
            const int n = 64 * g + jj;
            #pragma unroll
            for (int kt = 0; kt < 2; ++kt) {
                f16x8 v1, v2;
                #pragma unroll
                for (int j = 0; j < 8; ++j) {
                    const int k = kt * 32 + q * 8 + j;
                    v1[j] = (f16)(Wih1[n * H + k] * sc);
                    v2[j] = (f16)(Whh1[n * H + k] * sc);
                }
                wi1[kt][g] = v1; wh1[kt][g] = v2;
            }
            const float bu = (bih1[64 * g + jj] + bhh1[64 * g + jj]) * sc;
            bC1[g] = (f32x4){bu, bu, bu, bu};
        }
        f32x2 c01 = {0.f, 0.f}, c23 = {0.f, 0.f};

        #pragma unroll 4
        for (int m = 0; m < TT; ++m) {
            const int j  = m & 3;
            const int jp = (m - 1) & 3;   // == 3 at m==0 (zero slot)
            wait_ge(&flg[j], 4u * (unsigned)(m >> 2) + 4u);          // h0(m)
            if (m > 0) wait_ge(&flg[4 + jp], 4u * (unsigned)((m - 1) >> 2) + 4u); // h1(m-1)
            const f16* Nh = &H0r[j][0];
            const f16* Rh = &H1r[jp][0];
            f16x8 n0 = *(const f16x8*)&Nh[ar + 0  + ko];
            f16x8 n1 = *(const f16x8*)&Nh[ar + 32 + ko];
            f16x8 r0 = *(const f16x8*)&Rh[ar + 0  + ko];
            f16x8 r1 = *(const f16x8*)&Rh[ar + 32 + ko];
            bump(&flg[8 + j], lane0);   // h0(m) consumed (reads retired by bump's waitcnt)
            f32x4 accB[4];
            #pragma unroll
            for (int g = 0; g < 4; ++g) {
                f32x4 acc;
                acc = __builtin_amdgcn_mfma_f32_16x16x32_f16(n0, wi1[0][g], bC1[g], 0, 0, 0);
                acc = __builtin_amdgcn_mfma_f32_16x16x32_f16(n1, wi1[1][g], acc, 0, 0, 0);
                acc = __builtin_amdgcn_mfma_f32_16x16x32_f16(r0, wh1[0][g], acc, 0, 0, 0);
                acc = __builtin_amdgcn_mfma_f32_16x16x32_f16(r1, wh1[1][g], acc, 0, 0, 0);
                accB[g] = acc;
            }
            f32x2 h01 = lstm_cell2((f32x2){accB[0][0], accB[0][1]},
                                   (f32x2){accB[1][0], accB[1][1]},
                                   (f32x2){accB[2][0], accB[2][1]},
                                   (f32x2){accB[3][0], accB[3][1]}, c01);
            f32x2 h23 = lstm_cell2((f32x2){accB[0][2], accB[0][3]},
                                   (f32x2){accB[1][2], accB[1][3]},
                                   (f32x2){accB[2][2], accB[2][3]}, 
                                   (f32x2){accB[3][2], accB[3][3]}, c23);
            f16* Wh = &H1r[j][0];
            Wh[(q * 4 + 0) * HS + jj] = (f16)h01.x;
            Wh[(q * 4 + 1) * HS + jj] = (f16)h01.y;
            Wh[(q * 4 + 2) * HS + jj] = (f16)h23.x;
            Wh[(q * 4 + 3) * HS + jj] = (f16)h23.y;
            if (m == TT - 1) {
                hfin[q * 4 + 0][jj] = h01.x;
                hfin[q * 4 + 1][jj] = h01.y;
                hfin[q * 4 + 2][jj] = h23.x;
                hfin[q * 4 + 3][jj] = h23.y;
            }
            bump(&flg[4 + j], lane0);
        }
    }

    __syncthreads();   // h1(TT-1) visible to all

    // ---- FC epilogue ----
    if (t < NB * OUTD) {
        const int b = t / OUTD;
        const int o = t - b * OUTD;
        float a = bfc[o];
        #pragma unroll
        for (int j = 0; j < H; ++j)
            a += Wfc[o * H + j] * hfin[b][j];
        out[(size_t)(b0 + b) * OUTD + o] = a;
    }
}

extern "C" void kernel_launch(void* const* d_in, const int* in_sizes, int n_in,
                              void* d_out, int out_size, void* d_ws, size_t ws_size,
                              hipStream_t stream) {
    const float* x    = (const float*)d_in[0];
    const float* Wih0 = (const float*)d_in[1];
    const float* Whh0 = (const float*)d_in[2];
    const float* bih0 = (const float*)d_in[3];
    const float* bhh0 = (const float*)d_in[4];
    const float* Wih1 = (const float*)d_in[5];
    const float* Whh1 = (const float*)d_in[6];
    const float* bih1 = (const float*)d_in[7];
    const float* bhh1 = (const float*)d_in[8];
    const float* Wfc  = (const float*)d_in[9];
    const float* bfc  = (const float*)d_in[10];

    dim3 grid(BTOT / NB);   // 256 blocks, 1 per CU; 8 waves = 2 waves/SIMD
    dim3 block(512);
    lstm_ws<<<grid, block, 0, stream>>>(x, Wih0, Whh0, bih0, bhh0,
                                        Wih1, Whh1, bih1, bhh1,
                                        Wfc, bfc, (float*)d_out);
}

// Round 4
// 469.621 us; speedup vs baseline: 1.1066x; 1.0536x over previous
//
#include <hip/hip_runtime.h>

#define H    64
#define TT   512
#define NB   16
#define OUTD 3
#define BTOT 4096
#define INF  6
#define HS   72    // h plane row stride in f16 (144 B, keeps b128 aligned)
#define XS   32    // x plane row stride in f16; cols 6..31 stay zero

typedef _Float16 f16;
typedef _Float16 f16x8 __attribute__((ext_vector_type(8)));
typedef float    f32x4 __attribute__((ext_vector_type(4)));
typedef float    f32x2 __attribute__((ext_vector_type(2)));

#define LOG2E 1.44269504088896340736f
#define KSC   (2.0f * LOG2E)

static __device__ __forceinline__ f32x2 pk_fma(f32x2 a, f32x2 b, f32x2 c) {
#if __has_builtin(__builtin_elementwise_fma)
    return __builtin_elementwise_fma(a, b, c);
#else
    f32x2 r; r.x = __builtin_fmaf(a.x, b.x, c.x); r.y = __builtin_fmaf(a.y, b.y, c.y);
    return r;
#endif
}

static __device__ __forceinline__ f32x2 pk_min(f32x2 a, f32x2 b) {
#if __has_builtin(__builtin_elementwise_min)
    return __builtin_elementwise_min(a, b);
#else
    f32x2 r; r.x = fminf(a.x, b.x); r.y = fminf(a.y, b.y);
    return r;
#endif
}

// Fused LSTM cell update for a ROW PAIR (packed f32 ops). Pre-activations
// pre-scaled: ai,af,ao by log2e; ag by 2*log2e. C pre-scaled by 2*log2e,
// updated in place. 14 scalar transcendentals per pair = the VALU floor.
__device__ __forceinline__ f32x2 lstm_cell2(f32x2 ai, f32x2 af, f32x2 ag, f32x2 ao,
                                            f32x2& C) {
    f32x2 ei, ef, eg, eo;
    ei.x = __builtin_amdgcn_exp2f(ai.x); ei.y = __builtin_amdgcn_exp2f(ai.y);
    ef.x = __builtin_amdgcn_exp2f(af.x); ef.y = __builtin_amdgcn_exp2f(af.y);
    eg.x = __builtin_amdgcn_exp2f(ag.x); eg.y = __builtin_amdgcn_exp2f(ag.y);
    eo.x = __builtin_amdgcn_exp2f(ao.x); eo.y = __builtin_amdgcn_exp2f(ao.y);
    f32x2 A  = ei + 1.0f;
    f32x2 F  = ef + 1.0f;
    f32x2 Bp = eg + 1.0f;
    f32x2 G  = eg - 1.0f;
    f32x2 P  = A * Bp;
    f32x2 PF = P * F;
    f32x2 r1; r1.x = __builtin_amdgcn_rcpf(PF.x); r1.y = __builtin_amdgcn_rcpf(PF.y);
    f32x2 n1 = ef * C * P;
    f32x2 t2 = ei * G * F;
    f32x2 k2 = {KSC, KSC};
    C = pk_fma(k2, t2, n1) * r1;
    f32x2 clim = {126.0f, 126.0f};
    f32x2 Cc = pk_min(C, clim);
    f32x2 ec; ec.x = __builtin_amdgcn_exp2f(Cc.x); ec.y = __builtin_amdgcn_exp2f(Cc.y);
    f32x2 D2 = (eo + 1.0f) * (ec + 1.0f);
    f32x2 r2; r2.x = __builtin_amdgcn_rcpf(D2.x); r2.y = __builtin_amdgcn_rcpf(D2.y);
    return eo * (ec - 1.0f) * r2;
}

// FUSED layer pipeline: 256 threads = 4 waves, 1 wave/SIMD. Each wave owns 16
// hidden columns of BOTH layers; per slot s it computes h0(s) AND h1(s-1).
// All operands (h0(s-1), h1(s-2), x(s)) are ready at slot start -> ONE barrier
// per slot, no intra-slot rendezvous. Inside the single instruction stream the
// L1 MFMA chain overlaps the L0 cell transcendentals (separate pipes), which
// the 2-wave barrier-locked version could not do (phase-aligned waves).
// Planes: h0(s) -> H0[s&1]; h1(m) -> H1[m&1]; x(s) -> Xr[s&1].
__launch_bounds__(256, 1)
__global__ void lstm_fused(const float* __restrict__ x,
                           const float* __restrict__ Wih0, const float* __restrict__ Whh0,
                           const float* __restrict__ bih0, const float* __restrict__ bhh0,
                           const float* __restrict__ Wih1, const float* __restrict__ Whh1,
                           const float* __restrict__ bih1, const float* __restrict__ bhh1,
                           const float* __restrict__ Wfc,  const float* __restrict__ bfc,
                           float* __restrict__ out)
{
    __shared__ __align__(16) f16 H0[2][NB * HS];
    __shared__ __align__(16) f16 H1[2][NB * HS];
    __shared__ __align__(16) f16 Xr[2][NB * XS];
    __shared__ float hfin[NB][H + 1];

    const int t   = threadIdx.x;
    const int wv  = t >> 6;
    const int l15 = t & 15;
    const int q   = (t >> 4) & 3;
    const int jj  = 16 * wv + l15;   // hidden column this thread owns (all 4 gates, both layers)
    const int b0  = blockIdx.x * NB;
    const int ar  = l15 * HS;
    const int ko  = q * 8;

    // ---- zero planes ----
    for (int idx = t; idx < 2 * NB * HS; idx += 256) {
        (&H0[0][0])[idx] = (f16)0.0f;
        (&H1[0][0])[idx] = (f16)0.0f;
    }
    for (int idx = t; idx < 2 * NB * XS; idx += 256) (&Xr[0][0])[idx] = (f16)0.0f;
    __syncthreads();

    const bool loader = t < NB * INF;   // 96 threads (waves 0-1)
    const int  xb = t / INF;
    const int  xf = t - xb * INF;
    if (loader)
        Xr[0][xb * XS + xf] = (f16)x[((size_t)(b0 + xb) * TT) * INF + xf];

    // ---- weights, both layers, pre-scaled ----
    f16x8 wh0[2][4], wx0[4], wi1[2][4], wh1[2][4];
    f32x4 bC0[4], bC1[4];
    #pragma unroll
    for (int g = 0; g < 4; ++g) {
        const float sc = (g == 2) ? KSC : LOG2E;
        const int n = 64 * g + jj;
        #pragma unroll
        for (int kt = 0; kt < 2; ++kt) {
            f16x8 v0, v1, v2;
            #pragma unroll
            for (int j = 0; j < 8; ++j) {
                const int k = kt * 32 + q * 8 + j;
                v0[j] = (f16)(Whh0[n * H + k] * sc);
                v1[j] = (f16)(Wih1[n * H + k] * sc);
                v2[j] = (f16)(Whh1[n * H + k] * sc);
            }
            wh0[kt][g] = v0; wi1[kt][g] = v1; wh1[kt][g] = v2;
        }
        f16x8 vx;
        #pragma unroll
        for (int j = 0; j < 8; ++j)
            vx[j] = (q == 0 && j < INF) ? (f16)(Wih0[n * INF + j] * sc) : (f16)0.0f;
        wx0[g] = vx;
        const float bu0 = (bih0[64 * g + jj] + bhh0[64 * g + jj]) * sc;
        const float bu1 = (bih1[64 * g + jj] + bhh1[64 * g + jj]) * sc;
        bC0[g] = (f32x4){bu0, bu0, bu0, bu0};
        bC1[g] = (f32x4){bu1, bu1, bu1, bu1};
    }
    f32x2 c0a = {0.f, 0.f}, c0b = {0.f, 0.f};   // layer-0 cell state (rows q*4+0/1, +2/3)
    f32x2 c1a = {0.f, 0.f}, c1b = {0.f, 0.f};   // layer-1 cell state
    float xpre = 0.0f;
    __syncthreads();   // x(0) visible

    auto mfmaA = [&](f16x8 a0, f16x8 a1, f16x8 ax, f32x4* acc) {
        #pragma unroll
        for (int g = 0; g < 4; ++g) {
            f32x4 a = __builtin_amdgcn_mfma_f32_16x16x32_f16(a0, wh0[0][g], bC0[g], 0, 0, 0);
            a = __builtin_amdgcn_mfma_f32_16x16x32_f16(a1, wh0[1][g], a, 0, 0, 0);
            a = __builtin_amdgcn_mfma_f32_16x16x32_f16(ax, wx0[g],    a, 0, 0, 0);
            acc[g] = a;
        }
    };
    auto mfmaB = [&](f16x8 a0, f16x8 a1, f16x8 r0, f16x8 r1, f32x4* acc) {
        #pragma unroll
        for (int g = 0; g < 4; ++g) {
            f32x4 a = __builtin_amdgcn_mfma_f32_16x16x32_f16(a0, wi1[0][g], bC1[g], 0, 0, 0);
            a = __builtin_amdgcn_mfma_f32_16x16x32_f16(a1, wi1[1][g], a, 0, 0, 0);
            a = __builtin_amdgcn_mfma_f32_16x16x32_f16(r0, wh1[0][g], a, 0, 0, 0);
            a = __builtin_amdgcn_mfma_f32_16x16x32_f16(r1, wh1[1][g], a, 0, 0, 0);
            acc[g] = a;
        }
    };
    auto cellWrite = [&](f32x4* acc, f32x2& ca, f32x2& cb, f16* dst) {
        f32x2 h01 = lstm_cell2((f32x2){acc[0][0], acc[0][1]},
                               (f32x2){acc[1][0], acc[1][1]},
                               (f32x2){acc[2][0], acc[2][1]},
                               (f32x2){acc[3][0], acc[3][1]}, ca);
        f32x2 h23 = lstm_cell2((f32x2){acc[0][2], acc[0][3]},
                               (f32x2){acc[1][2], acc[1][3]},
                               (f32x2){acc[2][2], acc[2][3]}, 
                               (f32x2){acc[3][2], acc[3][3]}, cb);
        dst[(q * 4 + 0) * HS + jj] = (f16)h01.x;
        dst[(q * 4 + 1) * HS + jj] = (f16)h01.y;
        dst[(q * 4 + 2) * HS + jj] = (f16)h23.x;
        dst[(q * 4 + 3) * HS + jj] = (f16)h23.y;
    };

    // ---- slot 0: layer-0 only (h0(0)) ----
    {
        if (loader) xpre = x[((size_t)(b0 + xb) * TT + 1) * INF + xf];
        const f16* h0r = &H0[1][0];   // h0(-1) = zeros
        f16x8 a0 = *(const f16x8*)&h0r[ar + ko];
        f16x8 a1 = *(const f16x8*)&h0r[ar + 32 + ko];
        f16x8 ax = *(const f16x8*)&Xr[0][l15 * XS + ko];
        f32x4 accA[4];
        mfmaA(a0, a1, ax, accA);
        cellWrite(accA, c0a, c0b, &H0[0][0]);
        if (loader) Xr[1][xb * XS + xf] = (f16)xpre;
        __syncthreads();
    }

    // ---- main loop: slot s computes h0(s) and h1(s-1) ----
    #pragma unroll 2
    for (int s = 1; s < TT; ++s) {
        const int p = s & 1, pp = p ^ 1;
        if (loader) {
            const int tn = (s + 1 < TT) ? (s + 1) : (TT - 1);
            xpre = x[((size_t)(b0 + xb) * TT + tn) * INF + xf];
        }
        const f16* h0r = &H0[pp][0];   // h0(s-1)
        const f16* h1r = &H1[p][0];    // h1(s-2)
        f16x8 a0 = *(const f16x8*)&h0r[ar + ko];
        f16x8 a1 = *(const f16x8*)&h0r[ar + 32 + ko];
        f16x8 ax = *(const f16x8*)&Xr[p][l15 * XS + ko];
        f16x8 r0 = *(const f16x8*)&h1r[ar + ko];
        f16x8 r1 = *(const f16x8*)&h1r[ar + 32 + ko];
        f32x4 accA[4], accB[4];
        mfmaA(a0, a1, ax, accA);           // h0(s) gates   (A = h0(s-1), x(s))
        mfmaB(a0, a1, r0, r1, accB);       // h1(s-1) gates (A = h0(s-1), h1(s-2))
        cellWrite(accA, c0a, c0b, &H0[p][0]);    // write h0(s)
        cellWrite(accB, c1a, c1b, &H1[pp][0]);   // write h1(s-1), plane (s-1)&1
        if (loader) Xr[pp][xb * XS + xf] = (f16)xpre;   // x(s+1), plane (s+1)&1
        __syncthreads();
    }

    // ---- slot TT: layer-1 only (h1(TT-1)) ----
    {
        const f16* h0r = &H0[1][0];   // h0(TT-1), (TT-1)&1 == 1
        const f16* h1r = &H1[0][0];   // h1(TT-2), (TT-2)&1 == 0
        f16x8 a0 = *(const f16x8*)&h0r[ar + ko];
        f16x8 a1 = *(const f16x8*)&h0r[ar + 32 + ko];
        f16x8 r0 = *(const f16x8*)&h1r[ar + ko];
        f16x8 r1 = *(const f16x8*)&h1r[ar + 32 + ko];
        f32x4 accB[4];
        mfmaB(a0, a1, r0, r1, accB);
        f32x2 h01 = lstm_cell2((f32x2){accB[0][0], accB[0][1]},
                               (f32x2){accB[1][0], accB[1][1]},
                               (f32x2){accB[2][0], accB[2][1]},
                               (f32x2){accB[3][0], accB[3][1]}, c1a);
        f32x2 h23 = lstm_cell2((f32x2){accB[0][2], accB[0][3]},
                               (f32x2){accB[1][2], accB[1][3]},
                               (f32x2){accB[2][2], accB[2][3]},
                               (f32x2){accB[3][2], accB[3][3]}, c1b);
        hfin[q * 4 + 0][jj] = h01.x;
        hfin[q * 4 + 1][jj] = h01.y;
        hfin[q * 4 + 2][jj] = h23.x;
        hfin[q * 4 + 3][jj] = h23.y;
        __syncthreads();
    }

    // ---- FC epilogue ----
    if (t < NB * OUTD) {
        const int b = t / OUTD;
        const int o = t - b * OUTD;
        float a = bfc[o];
        #pragma unroll
        for (int j = 0; j < H; ++j)
            a += Wfc[o * H + j] * hfin[b][j];
        out[(size_t)(b0 + b) * OUTD + o] = a;
    }
}

extern "C" void kernel_launch(void* const* d_in, const int* in_sizes, int n_in,
                              void* d_out, int out_size, void* d_ws, size_t ws_size,
                              hipStream_t stream) {
    const float* x    = (const float*)d_in[0];
    const float* Wih0 = (const float*)d_in[1];
    const float* Whh0 = (const float*)d_in[2];
    const float* bih0 = (const float*)d_in[3];
    const float* bhh0 = (const float*)d_in[4];
    const float* Wih1 = (const float*)d_in[5];
    const float* Whh1 = (const float*)d_in[6];
    const float* bih1 = (const float*)d_in[7];
    const float* bhh1 = (const float*)d_in[8];
    const float* Wfc  = (const float*)d_in[9];
    const float* bfc  = (const float*)d_in[10];

    dim3 grid(BTOT / NB);   // 256 blocks, 1 per CU; 4 waves = 1 wave/SIMD
    dim3 block(256);
    lstm_fused<<<grid, block, 0, stream>>>(x, Wih0, Whh0, bih0, bhh0,
                                           Wih1, Whh1, bih1, bhh1,
                                           Wfc, bfc, (float*)d_out);
}